// Round 12
// baseline (470.597 us; speedup 1.0000x reference)
//
#include <hip/hip_runtime.h>
#include <hip/hip_bf16.h>
#include <hip/hip_fp16.h>

#define B_   16
#define S_   4096
#define D_   512
#define DH_  256
#define M_   (B_ * S_)      // 65536 rows
#define LC   64             // GARCH chunk length
#define NCH  (S_ / LC)      // 64 chunks

typedef _Float16 f16x8 __attribute__((ext_vector_type(8)));
typedef _Float16 f16x4 __attribute__((ext_vector_type(4)));
typedef float    f32x4 __attribute__((ext_vector_type(4)));

// -------- async global->LDS, 16B per lane (linear LDS dest, per-lane global src) -----
__device__ __forceinline__ void async_copy16(void* lds, const void* g) {
  __builtin_amdgcn_global_load_lds(
      (const __attribute__((address_space(1))) void*)g,
      (__attribute__((address_space(3))) void*)lds, 16, 0, 0);
}

// cheap softplus: max(x,0) + ln2*log2(1+2^(-|x|*log2e));
// exp2f/__log2f lower to near-bare v_exp_f32/v_log_f32 (validated R9/R10)
__device__ __forceinline__ float softplus_f(float x) {
  const float t = exp2f(-fabsf(x) * 1.44269504f);
  return fmaxf(x, 0.f) + 0.69314718f * __log2f(1.f + t);
}

// ------- weight transpose + f16 convert, both weights in one launch ---------------
// task < 256*512: W1T[f][d] = W1[d][f];  else: W2T[d][f] = W2[f][d]
__global__ void transpose_both_f16(const float* __restrict__ W1,
                                   const float* __restrict__ W2,
                                   _Float16* __restrict__ W1T,
                                   _Float16* __restrict__ W2T) {
  const int idx = blockIdx.x * 256 + threadIdx.x;
  if (idx < 256 * 512) {           // W1T: [256][512], src W1 [512][256]
    const int c = idx >> 9, r = idx & 511;          // c=f? no: idx = c*512 + r
    W1T[idx] = (_Float16)W1[(size_t)r * 256 + c];   // W1T[c][r] = W1[r][c]
  } else {                         // W2T: [512][256], src W2 [256][512]
    const int i2 = idx - 256 * 512;
    const int c = i2 >> 8, r = i2 & 255;
    W2T[i2] = (_Float16)W2[(size_t)r * 512 + c];    // W2T[c][r] = W2[r][c]
  }
}

// ---------------- GARCH phase 1: per-chunk affine coefficient C ---------------------
__global__ void garch_chunk(const float* __restrict__ ret,
                            const float* __restrict__ pal, const float* __restrict__ pbe,
                            const float* __restrict__ pom, float* __restrict__ Cws) {
  const int d  = threadIdx.x;          // 0..511
  const int bc = blockIdx.x;           // b*NCH + c
  const int b  = bc >> 6;
  const int c  = bc & (NCH - 1);
  const float al = pal[0], be = pbe[0], om = pom[0];
  const float* rp = ret + ((size_t)(b * S_ + c * LC)) * D_ + d;
  float Ca = 0.f;
#pragma unroll 8
  for (int j = 0; j < LC; j++) {
    const float r = rp[(size_t)j * D_];            // coalesced across d
    Ca = fmaf(be, Ca, fmaf(al, r * r, om));
  }
  Cws[(size_t)bc * D_ + d] = Ca;
}

// ---------------- GARCH phase 2: scan over chunks -> chunk-start states Vws ---------
__global__ void garch_scan(const float* __restrict__ pbe, const float* __restrict__ Cws,
                           float* __restrict__ Vws) {
  const int d = threadIdx.x;
  const int b = blockIdx.x;
  float A = pbe[0];
  A = A * A; A = A * A; A = A * A; A = A * A; A = A * A; A = A * A;   // beta^64
  float V = 0.01f;                                                     // INIT_VAR
  for (int c = 0; c < NCH; c++) {
    const size_t idx = ((size_t)(b * NCH + c)) * D_ + d;
    Vws[idx] = V;
    V = fmaf(A, V, Cws[idx]);
  }
}

// ---------------- f16 MFMA GEMM: 128x128 tile, BK=64, XOR-swizzled LDS --------------
// MODE 0: A = fp32 (convert in staging), out = relu(acc+bias) f16.  lb(256,4)
// MODE 1: A = f16 (global_load_lds); FUSED epilogue: stage f16(softplus(acc+bias)) in
//         32KB LDS, then per-column GARCH replay with 8-deep ret prefetch -> d_out.
//         lb(256,5): VGPR<=102, 5x32KB = 160KB LDS -> up to 5 blocks/CU.
template<int KDIM, int NOUT, int MODE>
__launch_bounds__(256, MODE ? 5 : 4)
__global__ void gemm_f16(const void* __restrict__ Ap, const _Float16* __restrict__ Bt,
                         const float* __restrict__ bias,
                         const float* __restrict__ retp,   // MODE1: ret base (else null)
                         const float* __restrict__ Vws_g,  // MODE1: chunk-start states
                         const float* __restrict__ gal, const float* __restrict__ gbe,
                         const float* __restrict__ gom,
                         void* outp) {
  __shared__ __align__(16) char smem[32768];
  _Float16* As = (_Float16*)smem;            // [128][64] f16, chunk ^= (row&7) swizzle
  _Float16* Bs = (_Float16*)(smem + 16384);  // B^T tile [n][k]

  const int tid  = threadIdx.x;
  const int lane = tid & 63;
  const int w    = tid >> 6;
  const int wm   = w >> 1, wn = w & 1;          // 2x2 wave grid, 64x64 per wave
  const size_t m0 = (size_t)blockIdx.x * 128;
  const int    n0 = blockIdx.y * 128;

  f32x4 acc[4][4];
#pragma unroll
  for (int i = 0; i < 4; i++)
#pragma unroll
    for (int j = 0; j < 4; j++)
      acc[i][j] = (f32x4){0.f, 0.f, 0.f, 0.f};

  const _Float16* hA = (const _Float16*)Ap;
  const float*    fA = (const float*)Ap;

  for (int kt = 0; kt < KDIM; kt += 64) {
    // ---- stage B (f16, pre-transposed): linear LDS dest + inverse-swizzled source ----
#pragma unroll
    for (int rr = 0; rr < 4; rr++) {
      const int task = rr * 256 + tid;
      const int row = task >> 3, pos = task & 7;
      const int dc = pos ^ (row & 7);
      async_copy16(&Bs[task * 8], &Bt[(size_t)(n0 + row) * KDIM + kt + dc * 8]);
    }
    if (MODE == 1) {
#pragma unroll
      for (int rr = 0; rr < 4; rr++) {
        const int task = rr * 256 + tid;
        const int row = task >> 3, pos = task & 7;
        const int dc = pos ^ (row & 7);
        async_copy16(&As[task * 8], &hA[(m0 + row) * (size_t)KDIM + kt + dc * 8]);
      }
    } else {
      // fp32 -> f16 reg-staged convert, swizzled ds_write_b128
#pragma unroll
      for (int rr = 0; rr < 4; rr++) {
        const int task = rr * 256 + tid;
        const int row = task >> 3, dc = task & 7;
        const float* sp = &fA[(m0 + row) * (size_t)KDIM + kt + dc * 8];
        const float4 v0 = *(const float4*)(sp);
        const float4 v1 = *(const float4*)(sp + 4);
        f16x8 hv;
        hv[0] = (_Float16)v0.x; hv[1] = (_Float16)v0.y;
        hv[2] = (_Float16)v0.z; hv[3] = (_Float16)v0.w;
        hv[4] = (_Float16)v1.x; hv[5] = (_Float16)v1.y;
        hv[6] = (_Float16)v1.z; hv[7] = (_Float16)v1.w;
        const int pos = dc ^ (row & 7);
        *(f16x8*)&As[row * 64 + pos * 8] = hv;
      }
    }
    __syncthreads();   // compiler drains vmcnt+lgkmcnt before s_barrier

    // ---- fragments (swizzled ds_read_b128, conflict-free) + MFMA ----
    f16x8 af[4][2], bf[4][2];
#pragma unroll
    for (int f = 0; f < 4; f++) {
#pragma unroll
      for (int kk = 0; kk < 2; kk++) {
        const int k8 = kk * 4 + (lane >> 4);
        const int ar = wm * 64 + f * 16 + (lane & 15);
        af[f][kk] = *(const f16x8*)&As[ar * 64 + ((k8 ^ (ar & 7)) * 8)];
        const int br = wn * 64 + f * 16 + (lane & 15);
        bf[f][kk] = *(const f16x8*)&Bs[br * 64 + ((k8 ^ (br & 7)) * 8)];
      }
    }
#pragma unroll
    for (int kk = 0; kk < 2; kk++)
#pragma unroll
      for (int fm = 0; fm < 4; fm++)
#pragma unroll
        for (int fn = 0; fn < 4; fn++)
          acc[fm][fn] = __builtin_amdgcn_mfma_f32_16x16x32_f16(af[fm][kk], bf[fn][kk],
                                                               acc[fm][fn], 0, 0, 0);
    __syncthreads();
  }

  if (MODE == 1) {
    // ---- fused epilogue: V + first ret group prefetched BEFORE staging barrier ----
    const int half = tid >> 7;
    const int col  = tid & 127;
    const int d    = n0 + col;
    const size_t mrow0 = m0 + half * 64;
    const int b  = (int)(m0 >> 12);                 // m0 / S_
    const int ch = (int)((m0 & 4095) >> 6) + half;  // chunk index within batch
    // issue these loads now: latency hides under 64 softplus + barrier
    float V = Vws_g[((size_t)(b * NCH + ch)) * D_ + d];
    float rbuf[8];
#pragma unroll
    for (int jj = 0; jj < 8; jj++)
      rbuf[jj] = retp[(mrow0 + jj) * (size_t)D_ + d];

    // stage f16(softplus(acc+bias)) [2][64][128]; XOR swizzle, write/read 2-way free
    _Float16* Ch = (_Float16*)smem;
#pragma unroll
    for (int fm = 0; fm < 4; fm++)
#pragma unroll
      for (int fn = 0; fn < 4; fn++) {
        const int colG = wn * 64 + fn * 16 + (lane & 15);
        const float bv = bias[n0 + colG];
#pragma unroll
        for (int j = 0; j < 4; j++) {
          const int rloc = fm * 16 + (lane >> 4) * 4 + j;
          const int colS = colG ^ (((rloc >> 2) & 3) << 4);
          Ch[wm * 8192 + rloc * 128 + colS] = (_Float16)softplus_f(acc[fm][fn][j] + bv);
        }
      }
    __syncthreads();

    // scan rows mrow0..+63 with 8-deep double-buffered ret prefetch (static reg idx)
    const float al = gal[0], be = gbe[0], om = gom[0];
    float* oo = (float*)outp;
    for (int j0 = 0; j0 < LC; j0 += 8) {
      float rnext[8];
      if (j0 + 8 < LC) {
#pragma unroll
        for (int jj = 0; jj < 8; jj++)
          rnext[jj] = retp[(mrow0 + j0 + 8 + jj) * (size_t)D_ + d];
      }
#pragma unroll
      for (int jj = 0; jj < 8; jj++) {
        const int j = j0 + jj;
        const int colS = col ^ (((j >> 2) & 3) << 4);
        const float sp = (float)Ch[half * 8192 + j * 128 + colS];
        oo[(mrow0 + j) * (size_t)D_ + d] = sp * V;          // 512B-coalesced across col
        const float r = rbuf[jj];
        V = fmaf(be, V, fmaf(al * r, r, om));
      }
#pragma unroll
      for (int jj = 0; jj < 8; jj++) rbuf[jj] = rnext[jj];
    }
  } else {
    // ---- MODE 0 epilogue: 2 passes over N-halves; stage in LDS, write coalesced ----
    float* Cs = (float*)smem;
    for (int p = 0; p < 2; ++p) {
      if (p) __syncthreads();             // previous pass read-out done
      if (wn == p) {
#pragma unroll
        for (int fm = 0; fm < 4; fm++) {
#pragma unroll
          for (int fn = 0; fn < 4; fn++) {
            const int colL = fn * 16 + (lane & 15);
            const float bv = bias[n0 + p * 64 + colL];
            const int c2 = colL ^ ((lane >> 4) << 4);
#pragma unroll
            for (int j = 0; j < 4; j++) {
              const int row = wm * 64 + fm * 16 + (lane >> 4) * 4 + j;
              Cs[row * 64 + c2] = acc[fm][fn][j] + bv;
            }
          }
        }
      }
      __syncthreads();
      // read-out: 128 rows x 16 float4; 8 float4 per thread
#pragma unroll
      for (int k = 0; k < 8; k++) {
        const int f   = k * 256 + tid;
        const int row = f >> 4;
        const int c0  = (f & 15) * 4;
        const int c2  = c0 ^ (((row >> 2) & 3) << 4);
        const f32x4 v = *(const f32x4*)&Cs[row * 64 + c2];
        const size_t gbase = (m0 + row) * (size_t)NOUT + n0 + p * 64 + c0;
        f16x4 hv;
        hv[0] = (_Float16)fmaxf(v[0], 0.f);
        hv[1] = (_Float16)fmaxf(v[1], 0.f);
        hv[2] = (_Float16)fmaxf(v[2], 0.f);
        hv[3] = (_Float16)fmaxf(v[3], 0.f);
        *(f16x4*)&((_Float16*)outp)[gbase] = hv;
      }
    }
  }
}

extern "C" void kernel_launch(void* const* d_in, const int* in_sizes, int n_in,
                              void* d_out, int out_size, void* d_ws, size_t ws_size,
                              hipStream_t stream) {
  const float* x     = (const float*)d_in[0];
  const float* rets  = (const float*)d_in[1];
  const float* alpha = (const float*)d_in[2];
  const float* beta  = (const float*)d_in[3];
  const float* omega = (const float*)d_in[4];
  const float* W1    = (const float*)d_in[5];
  const float* b1    = (const float*)d_in[6];
  const float* W2    = (const float*)d_in[7];
  const float* b2    = (const float*)d_in[8];
  float* out = (float*)d_out;

  // workspace layout (~36.5 MB total)
  char* ws = (char*)d_ws;
  _Float16* W1T = (_Float16*)ws;                               // [256][512] f16, 256 KB
  _Float16* W2T = (_Float16*)(ws + (256 << 10));               // [512][256] f16, 256 KB
  float*    Cws = (float*)(ws + (512 << 10));                  // [B][NCH][D] f32, 2 MB
  float*    Vws = (float*)(ws + (512 << 10) + (2 << 20));      // [B][NCH][D] f32, 2 MB
  _Float16* h   = (_Float16*)(ws + (512 << 10) + (4 << 20));   // [M][DH] f16, 32 MB

  // weight prep (single launch)
  transpose_both_f16<<<1024, 256, 0, stream>>>(W1, W2, W1T, W2T);

  // h = relu(x @ W1 + b1)  [f16 out]
  gemm_f16<512, 256, 0><<<dim3(M_ / 128, 2), 256, 0, stream>>>(
      x, W1T, b1, nullptr, nullptr, nullptr, nullptr, nullptr, h);

  // GARCH blocked affine scan: chunk coefficients + chunk-start states (replay fused
  // into gemm2's epilogue)
  garch_chunk <<<B_ * NCH, 512, 0, stream>>>(rets, alpha, beta, omega, Cws);
  garch_scan  <<<B_,       512, 0, stream>>>(beta, Cws, Vws);

  // out = softplus(h @ W2 + b2) * cond_var  (cv recomputed in-register from Vws+ret)
  gemm_f16<256, 512, 1><<<dim3(M_ / 128, 4), 256, 0, stream>>>(
      h, W2T, b2, rets, Vws, alpha, beta, omega, out);
}